// Round 2
// baseline (95.833 us; speedup 1.0000x reference)
//
#include <hip/hip_runtime.h>

#define B_ROWS   524288
#define C_COLS   128
#define THREADS  256
#define BLOCKS   2048
#define NWAVES   (BLOCKS * (THREADS / 64))   // 8192 waves; 262144 row-pairs / 8192 = 32 iters exactly

// DPP add helper: x += dpp_move(x, CTRL); invalid source lanes contribute 0
// (old=0 AND bound_ctrl=true covers both interpretations of bound_ctrl).
// CTRL must be a compile-time constant -> template parameter.
template <int CTRL>
__device__ __forceinline__ float dpp_add(float x) {
    union { float f; int i; } u, v;
    u.f = x;
    v.i = __builtin_amdgcn_update_dpp(0, u.i, CTRL, 0xF, 0xF, true);
    return x + v.f;
}

// Sum over each 32-lane half independently.
// row_shr:1,2,4,8 then row_bcast15. Result valid on lanes 31 and 63.
__device__ __forceinline__ float half_wave_reduce(float x) {
    x = dpp_add<0x111>(x);  // row_shr:1
    x = dpp_add<0x112>(x);  // row_shr:2
    x = dpp_add<0x114>(x);  // row_shr:4
    x = dpp_add<0x118>(x);  // row_shr:8
    x = dpp_add<0x142>(x);  // row_bcast15
    return x;
}

__global__ __launch_bounds__(THREADS) void loss_stage1(
        const float* __restrict__ logit,
        const int*   __restrict__ target,
        float*       __restrict__ partial) {
    const int tid  = blockIdx.x * THREADS + threadIdx.x;
    const int wave = tid >> 6;
    const int lane = threadIdx.x & 63;
    const int half = lane >> 5;   // 0 => row 2p, 1 => row 2p+1
    const int l32  = lane & 31;   // lane owns cols [4*l32, 4*l32+3]

    float acc = 0.0f;

    for (int pr = wave; pr < (B_ROWS / 2); pr += NWAVES) {
        const long long row  = (long long)pr * 2 + half;
        const long long base = row * C_COLS;

        const float4 x4 = *reinterpret_cast<const float4*>(logit  + base + l32 * 4);
        const int4   t4 = *reinterpret_cast<const int4*>(target + base + l32 * 4);

        float s_pos = 0.f, s_neg = 0.f, sum_pos = 0.f, n_pos = 0.f;

        // element 0: col = 4*l32 + 0. For l32==0 this is column 0:
        // it belongs to BOTH pos and neg masks and is excluded from n_pos/sum_pos.
        {
            const float e  = __expf(x4.x);
            const bool  c0 = (l32 == 0);
            const bool  tt = (t4.x != 0);
            s_pos   += (c0 ||  tt) ? e : 0.f;
            s_neg   += (c0 || !tt) ? e : 0.f;
            n_pos   += (!c0 && tt) ? 1.f  : 0.f;
            sum_pos += (!c0 && tt) ? x4.x : 0.f;
        }
        {
            const float e = __expf(x4.y);
            const bool tt = (t4.y != 0);
            s_pos   += tt ? e : 0.f;
            s_neg   += tt ? 0.f : e;
            n_pos   += tt ? 1.f : 0.f;
            sum_pos += tt ? x4.y : 0.f;
        }
        {
            const float e = __expf(x4.z);
            const bool tt = (t4.z != 0);
            s_pos   += tt ? e : 0.f;
            s_neg   += tt ? 0.f : e;
            n_pos   += tt ? 1.f : 0.f;
            sum_pos += tt ? x4.z : 0.f;
        }
        {
            const float e = __expf(x4.w);
            const bool tt = (t4.w != 0);
            s_pos   += tt ? e : 0.f;
            s_neg   += tt ? 0.f : e;
            n_pos   += tt ? 1.f : 0.f;
            sum_pos += tt ? x4.w : 0.f;
        }

        s_pos   = half_wave_reduce(s_pos);
        s_neg   = half_wave_reduce(s_neg);
        sum_pos = half_wave_reduce(sum_pos);
        n_pos   = half_wave_reduce(n_pos);

        if (l32 == 31) {  // lanes 31 (row 2p) and 63 (row 2p+1) hold the sums
            const float x0 = logit[base];    // L1 hit: same line lane 0/32 just loaded
            const int   t0 = target[base];
            const float e0 = __expf(x0);

            const float s_all   = s_pos + s_neg - e0;  // col0 was counted in both sides
            const float lse_all = __logf(s_all);
            const float lse_pos = __logf(s_pos);
            const float lse_neg = __logf(s_neg);

            const float loss_simple   = lse_all - x0;
            const float loss_positive = (n_pos * lse_pos - sum_pos) / fmaxf(n_pos, 1.0f);
            const float loss_full     = loss_positive + lse_neg - x0;

            acc += t0 ? loss_simple : loss_full;
        }
    }

    __shared__ float part[2 * (THREADS / 64)];
    const int wlocal = threadIdx.x >> 6;
    if (lane == 31) part[wlocal * 2 + 0] = acc;
    if (lane == 63) part[wlocal * 2 + 1] = acc;
    __syncthreads();
    if (threadIdx.x == 0) {
        float s = 0.f;
        #pragma unroll
        for (int i = 0; i < 2 * (THREADS / 64); ++i) s += part[i];
        partial[blockIdx.x] = s;
    }
}

__global__ __launch_bounds__(256) void loss_stage2(
        const float* __restrict__ partial,
        float*       __restrict__ out) {
    __shared__ float buf[256];
    float s = 0.f;
    for (int i = threadIdx.x; i < BLOCKS; i += 256) s += partial[i];
    buf[threadIdx.x] = s;
    __syncthreads();
    for (int off = 128; off > 0; off >>= 1) {
        if (threadIdx.x < off) buf[threadIdx.x] += buf[threadIdx.x + off];
        __syncthreads();
    }
    if (threadIdx.x == 0) out[0] = buf[0] * (1.0f / (float)B_ROWS);
}

extern "C" void kernel_launch(void* const* d_in, const int* in_sizes, int n_in,
                              void* d_out, int out_size, void* d_ws, size_t ws_size,
                              hipStream_t stream) {
    const float* logit  = (const float*)d_in[0];
    const int*   target = (const int*)d_in[1];
    float*       out    = (float*)d_out;
    float*       partial = (float*)d_ws;   // 2048 floats, fully rewritten every launch

    loss_stage1<<<BLOCKS, THREADS, 0, stream>>>(logit, target, partial);
    loss_stage2<<<1, 256, 0, stream>>>(partial, out);
}

// Round 3
// 92.045 us; speedup vs baseline: 1.0412x; 1.0412x over previous
//
#include <hip/hip_runtime.h>

#define B_ROWS   524288
#define C_COLS   128
#define THREADS  256
#define BLOCKS   2048
#define NWAVES   (BLOCKS * (THREADS / 64))   // 8192 waves
#define PAIRS    (B_ROWS / 2)                // 262144 row-pairs
#define ITERS    (PAIRS / NWAVES)            // 32, exact

typedef float f32x4 __attribute__((ext_vector_type(4)));
typedef int   i32x4 __attribute__((ext_vector_type(4)));

// DPP add helper: x += dpp_move(x, CTRL); invalid source lanes contribute 0.
template <int CTRL>
__device__ __forceinline__ float dpp_add(float x) {
    union { float f; int i; } u, v;
    u.f = x;
    v.i = __builtin_amdgcn_update_dpp(0, u.i, CTRL, 0xF, 0xF, true);
    return x + v.f;
}

// Sum over each 32-lane half independently; result valid on lanes 31 and 63.
__device__ __forceinline__ float half_wave_reduce(float x) {
    x = dpp_add<0x111>(x);  // row_shr:1
    x = dpp_add<0x112>(x);  // row_shr:2
    x = dpp_add<0x114>(x);  // row_shr:4
    x = dpp_add<0x118>(x);  // row_shr:8
    x = dpp_add<0x142>(x);  // row_bcast15
    return x;
}

// Broadcast lane 0 (resp. lane 32) of each 32-lane half to all lanes of that
// half. ds_swizzle BitMode: new_lane = ((i & and) | or) ^ xor, within 32-lane
// groups; and=or=xor=0 -> everyone reads lane 0 of their half. No LDS memory.
__device__ __forceinline__ float bcast0_f(float x) {
    union { float f; int i; } u, v;
    u.f = x;
    v.i = __builtin_amdgcn_ds_swizzle(u.i, 0x0000);
    return v.f;
}
__device__ __forceinline__ int bcast0_i(int x) {
    return __builtin_amdgcn_ds_swizzle(x, 0x0000);
}

struct Sums { float s_pos, s_neg, sum_pos, n_pos; };

// Per-lane partial sums over this lane's 4 columns. Column 0 (l32==0, elem 0)
// belongs to BOTH pos and neg masks and is excluded from n_pos/sum_pos.
__device__ __forceinline__ Sums row_sums(f32x4 x, i32x4 t, int l32) {
    Sums s = {0.f, 0.f, 0.f, 0.f};
    {
        const float e  = __expf(x[0]);
        const bool  c0 = (l32 == 0);
        const bool  tt = (t[0] != 0);
        s.s_pos   += (c0 ||  tt) ? e : 0.f;
        s.s_neg   += (c0 || !tt) ? e : 0.f;
        s.n_pos   += (!c0 && tt) ? 1.f  : 0.f;
        s.sum_pos += (!c0 && tt) ? x[0] : 0.f;
    }
    #pragma unroll
    for (int j = 1; j < 4; ++j) {
        const float e = __expf(x[j]);
        const bool tt = (t[j] != 0);
        s.s_pos   += tt ? e : 0.f;
        s.s_neg   += tt ? 0.f : e;
        s.n_pos   += tt ? 1.f : 0.f;
        s.sum_pos += tt ? x[j] : 0.f;
    }
    return s;
}

__device__ __forceinline__ float row_loss(const Sums& s, float x0, int t0) {
    const float e0      = __expf(x0);
    const float s_all   = s.s_pos + s.s_neg - e0;  // col0 counted on both sides
    const float lse_all = __logf(s_all);
    const float lse_pos = __logf(s.s_pos);
    const float lse_neg = __logf(s.s_neg);
    const float loss_simple   = lse_all - x0;
    const float loss_positive = (s.n_pos * lse_pos - s.sum_pos) / fmaxf(s.n_pos, 1.0f);
    const float loss_full     = loss_positive + lse_neg - x0;
    return t0 ? loss_simple : loss_full;
}

__global__ __launch_bounds__(THREADS) void loss_stage1(
        const float* __restrict__ logit,
        const int*   __restrict__ target,
        float*       __restrict__ partial) {
    const int tid  = blockIdx.x * THREADS + threadIdx.x;
    const int wave = tid >> 6;
    const int lane = threadIdx.x & 63;
    const int half = lane >> 5;   // 0 => row 2p, 1 => row 2p+1
    const int l32  = lane & 31;   // lane owns cols [4*l32, 4*l32+3]

    float acc = 0.0f;

    // All index math fits in int32: B*C = 2^26 elements.
    for (int it = 0; it < ITERS / 2; ++it) {
        const int pr0   = wave + (2 * it)     * NWAVES;
        const int pr1   = wave + (2 * it + 1) * NWAVES;
        const int base0 = (pr0 * 2 + half) * C_COLS;
        const int base1 = (pr1 * 2 + half) * C_COLS;

        // 4 nontemporal streaming loads in flight before any dependent use.
        const f32x4 xa = __builtin_nontemporal_load(
            reinterpret_cast<const f32x4*>(logit  + base0 + l32 * 4));
        const i32x4 ta = __builtin_nontemporal_load(
            reinterpret_cast<const i32x4*>(target + base0 + l32 * 4));
        const f32x4 xb = __builtin_nontemporal_load(
            reinterpret_cast<const f32x4*>(logit  + base1 + l32 * 4));
        const i32x4 tb = __builtin_nontemporal_load(
            reinterpret_cast<const i32x4*>(target + base1 + l32 * 4));

        Sums sa = row_sums(xa, ta, l32);
        Sums sb = row_sums(xb, tb, l32);

        // Grab col-0 values from lane 0/32's registers (no memory access).
        const float x0a = bcast0_f(xa[0]);
        const int   t0a = bcast0_i(ta[0]);
        const float x0b = bcast0_f(xb[0]);
        const int   t0b = bcast0_i(tb[0]);

        sa.s_pos   = half_wave_reduce(sa.s_pos);
        sa.s_neg   = half_wave_reduce(sa.s_neg);
        sa.sum_pos = half_wave_reduce(sa.sum_pos);
        sa.n_pos   = half_wave_reduce(sa.n_pos);
        sb.s_pos   = half_wave_reduce(sb.s_pos);
        sb.s_neg   = half_wave_reduce(sb.s_neg);
        sb.sum_pos = half_wave_reduce(sb.sum_pos);
        sb.n_pos   = half_wave_reduce(sb.n_pos);

        if (l32 == 31) {  // lanes 31 (row 2p) and 63 (row 2p+1) hold the sums
            acc += row_loss(sa, x0a, t0a);
            acc += row_loss(sb, x0b, t0b);
        }
    }

    __shared__ float part[2 * (THREADS / 64)];
    const int wlocal = threadIdx.x >> 6;
    if (lane == 31) part[wlocal * 2 + 0] = acc;
    if (lane == 63) part[wlocal * 2 + 1] = acc;
    __syncthreads();
    if (threadIdx.x == 0) {
        float s = 0.f;
        #pragma unroll
        for (int i = 0; i < 2 * (THREADS / 64); ++i) s += part[i];
        partial[blockIdx.x] = s;
    }
}

__global__ __launch_bounds__(256) void loss_stage2(
        const float* __restrict__ partial,
        float*       __restrict__ out) {
    __shared__ float buf[256];
    float s = 0.f;
    for (int i = threadIdx.x; i < BLOCKS; i += 256) s += partial[i];
    buf[threadIdx.x] = s;
    __syncthreads();
    for (int off = 128; off > 0; off >>= 1) {
        if (threadIdx.x < off) buf[threadIdx.x] += buf[threadIdx.x + off];
        __syncthreads();
    }
    if (threadIdx.x == 0) out[0] = buf[0] * (1.0f / (float)B_ROWS);
}

extern "C" void kernel_launch(void* const* d_in, const int* in_sizes, int n_in,
                              void* d_out, int out_size, void* d_ws, size_t ws_size,
                              hipStream_t stream) {
    const float* logit   = (const float*)d_in[0];
    const int*   target  = (const int*)d_in[1];
    float*       out     = (float*)d_out;
    float*       partial = (float*)d_ws;   // 2048 floats, fully rewritten every launch

    loss_stage1<<<BLOCKS, THREADS, 0, stream>>>(logit, target, partial);
    loss_stage2<<<1, 256, 0, stream>>>(partial, out);
}

// Round 5
// 88.271 us; speedup vs baseline: 1.0857x; 1.0428x over previous
//
#include <hip/hip_runtime.h>

#define B_ROWS   524288
#define C_COLS   128
#define THREADS  256
#define BLOCKS   2048
#define NWAVES   (BLOCKS * (THREADS / 64))   // 8192 waves
#define PAIRS    (B_ROWS / 2)                // 262144 row-pairs
#define ITERS    (PAIRS / NWAVES)            // 32 pairs owned per wave, exact
#define OUTER    (ITERS / 2)                 // 16 iterations, 2 adjacent pairs each

typedef float f32x4 __attribute__((ext_vector_type(4)));
typedef int   i32x4 __attribute__((ext_vector_type(4)));

// DPP add helper: x += dpp_move(x, CTRL); invalid source lanes contribute 0.
template <int CTRL>
__device__ __forceinline__ float dpp_add(float x) {
    union { float f; int i; } u, v;
    u.f = x;
    v.i = __builtin_amdgcn_update_dpp(0, u.i, CTRL, 0xF, 0xF, true);
    return x + v.f;
}

// Sum over each 32-lane half independently; result valid on lanes 31 and 63.
__device__ __forceinline__ float half_wave_reduce(float x) {
    x = dpp_add<0x111>(x);  // row_shr:1
    x = dpp_add<0x112>(x);  // row_shr:2
    x = dpp_add<0x114>(x);  // row_shr:4
    x = dpp_add<0x118>(x);  // row_shr:8
    x = dpp_add<0x142>(x);  // row_bcast15
    return x;
}

// Broadcast lane 0 (resp. 32) of each 32-lane half to that half (register-only).
__device__ __forceinline__ float bcast0_f(float x) {
    union { float f; int i; } u, v;
    u.f = x;
    v.i = __builtin_amdgcn_ds_swizzle(u.i, 0x0000);
    return v.f;
}
__device__ __forceinline__ int bcast0_i(int x) {
    return __builtin_amdgcn_ds_swizzle(x, 0x0000);
}

struct Sums { float s_pos, s_neg, sum_pos, n_pos; };

// Per-lane partial sums over this lane's 4 columns. Column 0 (l32==0, elem 0)
// belongs to BOTH pos and neg masks and is excluded from n_pos/sum_pos.
__device__ __forceinline__ Sums row_sums(f32x4 x, i32x4 t, int l32) {
    Sums s;
    {
        const float e  = __expf(x[0]);
        const bool  c0 = (l32 == 0);
        const bool  tt = (t[0] != 0);
        s.s_pos   = (c0 ||  tt) ? e : 0.f;
        s.s_neg   = (c0 || !tt) ? e : 0.f;
        s.n_pos   = (!c0 && tt) ? 1.f  : 0.f;
        s.sum_pos = (!c0 && tt) ? x[0] : 0.f;
    }
    #pragma unroll
    for (int j = 1; j < 4; ++j) {
        const float e = __expf(x[j]);
        const float f = (t[j] != 0) ? 1.f : 0.f;   // one select
        const float p = f * e;                      // pos share
        s.s_pos   += p;
        s.s_neg   += e - p;
        s.n_pos   += f;
        s.sum_pos  = fmaf(f, x[j], s.sum_pos);
    }
    return s;
}

__device__ __forceinline__ float row_loss(const Sums& s, float x0, int t0) {
    const float e0      = __expf(x0);
    const float s_all   = s.s_pos + s.s_neg - e0;  // col0 counted on both sides
    const float lse_all = __logf(s_all);
    const float lse_pos = __logf(s.s_pos);
    const float lse_neg = __logf(s.s_neg);
    const float loss_simple   = lse_all - x0;
    const float loss_positive = (s.n_pos * lse_pos - s.sum_pos) / fmaxf(s.n_pos, 1.0f);
    const float loss_full     = loss_positive + lse_neg - x0;
    return t0 ? loss_simple : loss_full;
}

// Contiguous-per-wave mapping: wave w owns pairs [w*ITERS, (w+1)*ITERS);
// each iteration consumes 2 ADJACENT pairs -> 4 consecutive rows = one
// sequential 2 KiB logit chunk + 2 KiB target chunk per wave per iter.
__device__ __forceinline__ void load4(const float* __restrict__ logit,
                                      const int*   __restrict__ target,
                                      int wave, int half, int l32, int it,
                                      f32x4& xa, i32x4& ta, f32x4& xb, i32x4& tb) {
    const int pr0   = wave * ITERS + 2 * it;
    const int base0 = (pr0 * 2 + half) * C_COLS + l32 * 4;
    const int base1 = base0 + 2 * C_COLS;          // pr1 = pr0 + 1
    xa = __builtin_nontemporal_load(reinterpret_cast<const f32x4*>(logit  + base0));
    ta = __builtin_nontemporal_load(reinterpret_cast<const i32x4*>(target + base0));
    xb = __builtin_nontemporal_load(reinterpret_cast<const f32x4*>(logit  + base1));
    tb = __builtin_nontemporal_load(reinterpret_cast<const i32x4*>(target + base1));
}

__device__ __forceinline__ void body(f32x4 xa, i32x4 ta, f32x4 xb, i32x4 tb,
                                     int l32, float& acc) {
    Sums sa = row_sums(xa, ta, l32);
    Sums sb = row_sums(xb, tb, l32);

    // col-0 values from lane 0/32's registers (no memory access)
    const float x0a = bcast0_f(xa[0]);
    const int   t0a = bcast0_i(ta[0]);
    const float x0b = bcast0_f(xb[0]);
    const int   t0b = bcast0_i(tb[0]);

    sa.s_pos   = half_wave_reduce(sa.s_pos);
    sa.s_neg   = half_wave_reduce(sa.s_neg);
    sa.sum_pos = half_wave_reduce(sa.sum_pos);
    sa.n_pos   = half_wave_reduce(sa.n_pos);
    sb.s_pos   = half_wave_reduce(sb.s_pos);
    sb.s_neg   = half_wave_reduce(sb.s_neg);
    sb.sum_pos = half_wave_reduce(sb.sum_pos);
    sb.n_pos   = half_wave_reduce(sb.n_pos);

    if (l32 == 31) {  // lanes 31 (row 2p) and 63 (row 2p+1) hold the sums
        acc += row_loss(sa, x0a, t0a);
        acc += row_loss(sb, x0b, t0b);
    }
}

__global__ __launch_bounds__(THREADS) void loss_stage1(
        const float* __restrict__ logit,
        const int*   __restrict__ target,
        float*       __restrict__ partial) {
    const int tid  = blockIdx.x * THREADS + threadIdx.x;
    const int wave = tid >> 6;
    const int lane = threadIdx.x & 63;
    const int half = lane >> 5;   // 0 => row 2p, 1 => row 2p+1
    const int l32  = lane & 31;   // lane owns cols [4*l32, 4*l32+3]

    float acc = 0.0f;

    // 1-deep software pipeline: iter k+1's loads issued before iter k's compute.
    f32x4 xa, xb; i32x4 ta, tb;
    load4(logit, target, wave, half, l32, 0, xa, ta, xb, tb);
    for (int it = 0; it < OUTER - 1; ++it) {
        f32x4 nxa, nxb; i32x4 nta, ntb;
        load4(logit, target, wave, half, l32, it + 1, nxa, nta, nxb, ntb);
        body(xa, ta, xb, tb, l32, acc);
        xa = nxa; ta = nta; xb = nxb; tb = ntb;
    }
    body(xa, ta, xb, tb, l32, acc);  // peeled last iteration

    __shared__ float part[2 * (THREADS / 64)];
    const int wlocal = threadIdx.x >> 6;
    if (lane == 31) part[wlocal * 2 + 0] = acc;
    if (lane == 63) part[wlocal * 2 + 1] = acc;
    __syncthreads();
    if (threadIdx.x == 0) {
        float s = 0.f;
        #pragma unroll
        for (int i = 0; i < 2 * (THREADS / 64); ++i) s += part[i];
        partial[blockIdx.x] = s;
    }
}

__global__ __launch_bounds__(256) void loss_stage2(
        const float* __restrict__ partial,
        float*       __restrict__ out) {
    __shared__ float buf[256];
    float s = 0.f;
    for (int i = threadIdx.x; i < BLOCKS; i += 256) s += partial[i];
    buf[threadIdx.x] = s;
    __syncthreads();
    for (int off = 128; off > 0; off >>= 1) {
        if (threadIdx.x < off) buf[threadIdx.x] += buf[threadIdx.x + off];
        __syncthreads();
    }
    if (threadIdx.x == 0) out[0] = buf[0] * (1.0f / (float)B_ROWS);
}

extern "C" void kernel_launch(void* const* d_in, const int* in_sizes, int n_in,
                              void* d_out, int out_size, void* d_ws, size_t ws_size,
                              hipStream_t stream) {
    const float* logit   = (const float*)d_in[0];
    const int*   target  = (const int*)d_in[1];
    float*       out     = (float*)d_out;
    float*       partial = (float*)d_ws;   // 2048 floats, fully rewritten every launch

    loss_stage1<<<BLOCKS, THREADS, 0, stream>>>(logit, target, partial);
    loss_stage2<<<1, 256, 0, stream>>>(partial, out);
}